// Round 6
// baseline (42.199 us; speedup 1.0000x reference)
//
#include <hip/hip_runtime.h>

#define IMG_W 256
#define IMG_H 256
#define EPSN 1e-7f
#define INV_SIG2 50.0f      // 1 / (2 * 0.1^2)
#define NB 16               // batch
#define NN 64               // strokes per image
#define NC 3                // channels
#define PH 32
#define PW 32
#define WIN 36              // stroke footprint window (all nonzero f32 taps)
#define ROWP 36             // LDS patch row stride

#define TILE_W 64
#define TILE_H 8
#define TPI ((IMG_W / TILE_W) * (IMG_H / TILE_H))   // 128 tiles per image
#define NWG (NB * TPI)                              // 2048 gather blocks

// ws layout (bytes)
#define WS_GXY 0                                    // float2[1024]
#define WS_W   8192                                 // W[1024][3][36][36] f32 = 15.9 MB

// ---------------- kernel 1: per-stroke full window precompute --------------
// Produces W[n][c][yl][xl] = sum_p Fy[yl][p] * (sum_q Fx[xl][q] * patch[c][p][q]) / N
// Stage C -> LDS t_s, stage D fused (4-tap sparsity both axes).
__global__ __launch_bounds__(128)
void precomp_kernel(const float* __restrict__ brushes,
                    const float* __restrict__ patches,
                    float2* __restrict__ gxy,
                    float* __restrict__ W) {
    __shared__ float patch_s[NC][PH][ROWP];   // 13.8 KB
    __shared__ float t_s[NC][PH][WIN];        // 13.8 KB  [c][p][xl]
    __shared__ float den_x[PW];
    __shared__ float den_y[PH];
    __shared__ float4 fyw_s[WIN];
    __shared__ int   fyp_s[WIN];
    __shared__ float g_s[2];

    const int blk = blockIdx.x;               // stroke index b*64+n
    const int b   = blk >> 6;
    const int n   = blk & 63;
    const int tid = threadIdx.x;
    const float* P = patches + (size_t)blk * (NC * PH * PW);

    // fused per-image min/max normalization (wave 0)
    if (tid < 64) {
        float2 v = ((const float2*)brushes)[b * NN + tid];
        float mnx = v.x, mxx = v.x, mny = v.y, mxy = v.y;
        #pragma unroll
        for (int off = 32; off > 0; off >>= 1) {
            mnx = fminf(mnx, __shfl_xor(mnx, off));
            mxx = fmaxf(mxx, __shfl_xor(mxx, off));
            mny = fminf(mny, __shfl_xor(mny, off));
            mxy = fmaxf(mxy, __shfl_xor(mxy, off));
        }
        if (tid == n) {
            float gx = (v.x - mnx) / (mxx - mnx + EPSN) * (float)IMG_W;
            float gy = (v.y - mny) / (mxy - mny + EPSN) * (float)IMG_H;
            g_s[0] = gx; g_s[1] = gy;
            gxy[blk] = make_float2(gx, gy);
        }
    }

    // stage patch -> LDS (float4, padded rows)
    for (int i = tid; i < NC * PH * PW / 4; i += 128) {
        float4 v = ((const float4*)P)[i];
        int base = i * 4;
        int c = base >> 10;
        int r = base & 1023;
        int p = r >> 5, q = r & 31;
        *(float4*)&patch_s[c][p][q] = v;
    }
    __syncthreads();

    const float gx = g_s[0];
    const float gy = g_s[1];
    const int ix0 = (int)floorf(gx) - 17;
    const int iy0 = (int)floorf(gy) - 17;

    // normalization denominators (4 taps hold all nonzero f32 terms)
    if (tid < PW) {
        float cx = gx + (float)tid - 15.5f;   // ux_q = gx + (q+1) - 16.5
        int f = (int)floorf(cx);
        float s = 0.f;
        #pragma unroll
        for (int t = -1; t <= 2; ++t) {
            int a = f + t;
            if (a >= -16 && a <= IMG_W + 15) {
                float d = (float)a - cx;
                s += expf(-(d * d) * INV_SIG2);
            }
        }
        den_x[tid] = 1.f / (s + EPSN);
    } else if (tid < 2 * PW) {
        int p = tid - PW;
        float cy = gy + (float)p - 15.4f;     // uy_p = gy + (p+1) - 16.4
        int f = (int)floorf(cy);
        float s = 0.f;
        #pragma unroll
        for (int t = -1; t <= 2; ++t) {
            int a = f + t;
            if (a >= -16 && a <= IMG_H + 15) {
                float d = (float)a - cy;
                s += expf(-(d * d) * INV_SIG2);
            }
        }
        den_y[p] = 1.f / (s + EPSN);
    }
    __syncthreads();

    // compact 4-tap Fy rows -> LDS (scaled by den_y and 1/N)
    if (tid < WIN) {
        float z = (float)(iy0 + tid) - gy + 15.4f;
        int p0 = min(max((int)floorf(z) - 1, 0), PH - 4);
        float d0 = z - (float)(p0 + 0);
        float d1 = z - (float)(p0 + 1);
        float d2 = z - (float)(p0 + 2);
        float d3 = z - (float)(p0 + 3);
        float4 w;
        w.x = expf(-(d0 * d0) * INV_SIG2) * den_y[p0 + 0] * (1.0f / NN);
        w.y = expf(-(d1 * d1) * INV_SIG2) * den_y[p0 + 1] * (1.0f / NN);
        w.z = expf(-(d2 * d2) * INV_SIG2) * den_y[p0 + 2] * (1.0f / NN);
        w.w = expf(-(d3 * d3) * INV_SIG2) * den_y[p0 + 3] * (1.0f / NN);
        fyw_s[tid] = w;
        fyp_s[tid] = p0;
    }

    const int cc = tid / WIN;                 // channel
    const int xl = tid - cc * WIN;            // window column
    const bool active = (tid < NC * WIN);

    // stage C (4-tap): t_s[c][p][xl] = sum_q Fx * patch
    if (active) {
        float zx = (float)(ix0 + xl) - gx + 15.5f;
        int q0 = min(max((int)floorf(zx) - 1, 0), PW - 4);
        float e0 = zx - (float)(q0 + 0);
        float e1 = zx - (float)(q0 + 1);
        float e2 = zx - (float)(q0 + 2);
        float e3 = zx - (float)(q0 + 3);
        float w0 = expf(-(e0 * e0) * INV_SIG2) * den_x[q0 + 0];
        float w1 = expf(-(e1 * e1) * INV_SIG2) * den_x[q0 + 1];
        float w2 = expf(-(e2 * e2) * INV_SIG2) * den_x[q0 + 2];
        float w3 = expf(-(e3 * e3) * INV_SIG2) * den_x[q0 + 3];

        const float* pr = &patch_s[cc][0][q0];
        #pragma unroll
        for (int p = 0; p < PH; ++p) {
            float s = w0 * pr[p * ROWP + 0] + w1 * pr[p * ROWP + 1]
                    + w2 * pr[p * ROWP + 2] + w3 * pr[p * ROWP + 3];
            t_s[cc][p][xl] = s;
        }
    }
    __syncthreads();

    // stage D (4-tap, fused): W[n][c][yl][xl] = sum_j fyw[yl][j] * t[p0+j][xl]
    if (active) {
        float* Wb = W + ((size_t)blk * NC + cc) * (WIN * WIN) + xl;
        const float* tc = &t_s[cc][0][xl];
        #pragma unroll
        for (int yl = 0; yl < WIN; ++yl) {
            int p0   = fyp_s[yl];             // broadcast
            float4 w = fyw_s[yl];             // broadcast
            const float* tp = tc + p0 * WIN;  // runtime offset -> LDS, not regs
            float s = w.x * tp[0]       + w.y * tp[WIN]
                    + w.z * tp[2 * WIN] + w.w * tp[3 * WIN];
            Wb[yl * WIN] = s;                 // coalesced 144B per (c,yl)
        }
    }
}

// ---------------- kernel 2: gather = sum of overlapping windows ------------
// 1 load + 1 add per (stroke, output element). No atomics, no fill.
__global__ __launch_bounds__(192)
void gather_kernel(const float2* __restrict__ gxy,
                   const float* __restrict__ W,
                   float* __restrict__ out) {
    __shared__ int sPack[NN];
    __shared__ int sCnt;

    // XCD-contiguous swizzle: each XCD owns 256 consecutive tiles = 2 images
    int blk = blockIdx.x;
    blk = (blk & 7) * (NWG >> 3) + (blk >> 3);

    const int b   = blk >> 7;                 // image
    const int t7  = blk & 127;
    const int ty0 = (t7 >> 2) * TILE_H;
    const int tx0 = (t7 & 3) * TILE_W;
    const int tid = threadIdx.x;
    const int cc  = tid >> 6;                 // channel
    const int xg  = tx0 + (tid & 63);         // owned x column

    // wave 0: ballot-compacted overlap list
    if (tid < 64) {
        float2 g = gxy[b * NN + tid];
        int ix0 = (int)floorf(g.x) - 17;
        int iy0 = (int)floorf(g.y) - 17;
        bool ov = (ix0 <= tx0 + TILE_W - 1) && (ix0 + WIN - 1 >= tx0) &&
                  (iy0 <= ty0 + TILE_H - 1) && (iy0 + WIN - 1 >= ty0);
        unsigned long long m = __ballot(ov);
        if (ov) {
            int pos = __popcll(m & ((1ull << tid) - 1));
            sPack[pos] = tid | ((ix0 + 17) << 6) | ((iy0 + 17) << 15);
        }
        if (tid == 0) sCnt = (int)__popcll(m);
    }
    __syncthreads();
    const int cnt = sCnt;

    float acc[TILE_H];
    #pragma unroll
    for (int i = 0; i < TILE_H; ++i) acc[i] = 0.f;

    for (int i = 0; i < cnt; ++i) {
        const int pk  = sPack[i];
        const int n   = pk & 63;
        const int ix0 = ((pk >> 6) & 511) - 17;
        const int iy0 = ((pk >> 15) & 511) - 17;

        const int xl = xg - ix0;
        if ((unsigned)xl >= (unsigned)WIN) continue;

        const float* Wn = W + ((size_t)(b * NN + n) * NC + cc) * (WIN * WIN) + xl;
        #pragma unroll
        for (int yi = 0; yi < TILE_H; ++yi) {
            int yl = ty0 + yi - iy0;          // block-uniform
            if ((unsigned)yl < (unsigned)WIN)
                acc[yi] += Wn[yl * WIN];      // 1 load + 1 add
        }
    }

    // coalesced final store; tiles partition the image
    float* o = out + (((size_t)b * NC + cc) * IMG_H + ty0) * IMG_W + xg;
    #pragma unroll
    for (int yi = 0; yi < TILE_H; ++yi)
        o[(size_t)yi * IMG_W] = acc[yi];
}

extern "C" void kernel_launch(void* const* d_in, const int* in_sizes, int n_in,
                              void* d_out, int out_size, void* d_ws, size_t ws_size,
                              hipStream_t stream) {
    const float* brushes = (const float*)d_in[0];   // (16, 64, 2) f32
    const float* patches = (const float*)d_in[1];   // (16, 64, 3, 32, 32) f32
    float* out = (float*)d_out;                     // (16, 3, 256, 256) f32

    char* ws = (char*)d_ws;
    float2* gxy = (float2*)(ws + WS_GXY);
    float*  W   = (float*) (ws + WS_W);

    precomp_kernel<<<NB * NN, 128, 0, stream>>>(brushes, patches, gxy, W);
    gather_kernel<<<NWG, 192, 0, stream>>>(gxy, W, out);
}

// Round 7
// 32.068 us; speedup vs baseline: 1.3159x; 1.3159x over previous
//
#include <hip/hip_runtime.h>

#define IMG_W 256
#define IMG_H 256
#define EPSN 1e-7f
#define INV_SIG2 50.0f      // 1 / (2 * 0.1^2)
#define NB 16               // batch
#define NN 64               // strokes per image
#define NC 3                // channels
#define PH 32
#define PW 32
#define WIN 36              // stroke footprint window (all nonzero f32 taps)
#define PROWS 12            // staged patch rows per stroke (covers 8 y + 4 taps)
#define PRP 36              // padded q stride (144B, 16B-aligned)

#define TILE_W 64
#define TILE_H 8
#define TPI 128             // tiles per image: 4 x-tiles * 32 y-tiles
#define NWG (NB * TPI)      // 2048 blocks

// One block per 64x8 output tile. Fully fused: norm + ballot stroke list +
// per-stroke 4x4-tap separable splat, accumulated in registers.
// No intermediate global buffers, no atomics; out written exactly once.
__global__ __launch_bounds__(192)
void fused_kernel(const float* __restrict__ brushes,
                  const float* __restrict__ patches,
                  float* __restrict__ out) {
    __shared__ float2 gxy_s[NN];
    __shared__ int    sPack[NN];
    __shared__ int    sCnt;
    __shared__ float  patch_s[NC][PROWS][PRP];  // 5.2 KB, staged rows of 1 stroke
    __shared__ float  den_x[PW];
    __shared__ float4 fyw_s[TILE_H];            // per tile-row 4 Fy taps
    __shared__ int    fyp_s[TILE_H];            // tap start p0
    __shared__ float  t_s[PROWS][192];          // per-lane t columns (9.2 KB)

    // XCD-contiguous swizzle: each XCD owns 256 consecutive tiles = 2 images
    int blk = blockIdx.x;
    blk = (blk & 7) * (NWG >> 3) + (blk >> 3);

    const int b   = blk >> 7;                   // image
    const int t7  = blk & 127;
    const int ty0 = (t7 >> 2) * TILE_H;
    const int tx0 = (t7 & 3) * TILE_W;
    const int tid = threadIdx.x;
    const int cc  = tid >> 6;                   // channel (wave index)
    const int xg  = tx0 + (tid & 63);           // owned x column (always in-image)

    // --- wave 0: fused per-image min/max norm + ballot overlap list ---
    if (tid < 64) {
        float2 v = ((const float2*)brushes)[b * NN + tid];
        float mnx = v.x, mxx = v.x, mny = v.y, mxy = v.y;
        #pragma unroll
        for (int off = 32; off > 0; off >>= 1) {
            mnx = fminf(mnx, __shfl_xor(mnx, off));
            mxx = fmaxf(mxx, __shfl_xor(mxx, off));
            mny = fminf(mny, __shfl_xor(mny, off));
            mxy = fmaxf(mxy, __shfl_xor(mxy, off));
        }
        float gx = (v.x - mnx) / (mxx - mnx + EPSN) * (float)IMG_W;
        float gy = (v.y - mny) / (mxy - mny + EPSN) * (float)IMG_H;
        gxy_s[tid] = make_float2(gx, gy);

        int ix0 = (int)floorf(gx) - 17;
        int iy0 = (int)floorf(gy) - 17;
        bool ov = (ix0 <= tx0 + TILE_W - 1) && (ix0 + WIN - 1 >= tx0) &&
                  (iy0 <= ty0 + TILE_H - 1) && (iy0 + WIN - 1 >= ty0);
        unsigned long long m = __ballot(ov);
        if (ov) {
            int pos = __popcll(m & ((1ull << tid) - 1));
            sPack[pos] = tid | ((ix0 + 17) << 6) | ((iy0 + 17) << 15);
        }
        if (tid == 0) sCnt = (int)__popcll(m);
    }
    __syncthreads();
    const int cnt = sCnt;

    float acc[TILE_H];
    #pragma unroll
    for (int i = 0; i < TILE_H; ++i) acc[i] = 0.f;

    for (int i = 0; i < cnt; ++i) {
        const int pk  = sPack[i];
        const int n   = pk & 63;
        const int ix0 = ((pk >> 6) & 511) - 17;
        const int iy0 = ((pk >> 15) & 511) - 17;
        const float2 g = gxy_s[n];              // LDS broadcast

        // block-uniform staged-row base: covers p0(yl)..p0(yl)+3 for all tile rows
        const int yl_lo  = max(ty0 - iy0, 0);
        const float z_lo = (float)(iy0 + yl_lo) - g.y + 15.4f;
        const int p0_lo  = min(max((int)floorf(z_lo) - 1, 0), PH - 4);
        const int pbase  = min(p0_lo, PH - PROWS);   // <= 20

        // ---- phase A: stage 12 patch rows + den_x + compact Fy taps ----
        const float* P = patches + (size_t)(b * NN + n) * (NC * PH * PW);
        for (int u = tid; u < NC * PROWS * 8; u += 192) {   // 288 float4 loads
            int c  = u / (PROWS * 8);
            int r  = u - c * (PROWS * 8);
            int pr = r >> 3, q4 = (r & 7) << 2;
            float4 v = *(const float4*)(P + ((size_t)c * PH + pbase + pr) * PW + q4);
            *(float4*)&patch_s[c][pr][q4] = v;
        }
        if (tid < PW) {
            // den_x[q]: 4 taps hold all nonzero f32 terms of the [-16,271] sum
            float cx = g.x + (float)tid - 15.5f;            // ux_q = gx + q - 15.5
            int f = (int)floorf(cx);
            float s = 0.f;
            #pragma unroll
            for (int t = -1; t <= 2; ++t) {
                int a = f + t;
                if (a >= -16 && a <= IMG_W + 15) {
                    float d = (float)a - cx;
                    s += expf(-(d * d) * INV_SIG2);
                }
            }
            den_x[tid] = 1.f / (s + EPSN);
        } else if (tid >= 64 && tid < 64 + TILE_H * 4) {
            // Fy taps for the 8 tile rows (4 lanes per row, den_y inline)
            int r  = tid - 64;
            int yi = r >> 2, j = r & 3;
            int yl = ty0 + yi - iy0;
            float w = 0.f;
            int p0 = 0;
            if ((unsigned)yl < (unsigned)WIN) {
                float z = (float)(iy0 + yl) - g.y + 15.4f;  // z - p at tap p
                p0 = min(max((int)floorf(z) - 1, 0), PH - 4);
                int p = p0 + j;
                float cy = g.y + (float)p - 15.4f;
                int f = (int)floorf(cy);
                float s = 0.f;
                #pragma unroll
                for (int t = -1; t <= 2; ++t) {
                    int a = f + t;
                    if (a >= -16 && a <= IMG_H + 15) {
                        float d = (float)a - cy;
                        s += expf(-(d * d) * INV_SIG2);
                    }
                }
                float dz = z - (float)p;
                w = expf(-(dz * dz) * INV_SIG2) / (s + EPSN) * (1.0f / (float)NN);
            }
            ((float*)&fyw_s[yi])[j] = w;
            if (j == 0) fyp_s[yi] = p0;
        }
        __syncthreads();

        // ---- phase B: per-lane 4-tap x-filter into t_s, then 4-tap y into acc ----
        const int xl = xg - ix0;
        if ((unsigned)xl < (unsigned)WIN) {
            float zx = (float)xg - g.x + 15.5f;             // zx - q at tap q
            int q0 = min(max((int)floorf(zx) - 1, 0), PW - 4);
            float e0 = zx - (float)q0;
            float w0 = expf(-(e0 * e0) * INV_SIG2) * den_x[q0 + 0];
            float e1 = e0 - 1.f;
            float w1 = expf(-(e1 * e1) * INV_SIG2) * den_x[q0 + 1];
            float e2 = e0 - 2.f;
            float w2 = expf(-(e2 * e2) * INV_SIG2) * den_x[q0 + 2];
            float e3 = e0 - 3.f;
            float w3 = expf(-(e3 * e3) * INV_SIG2) * den_x[q0 + 3];

            const float* pr = &patch_s[cc][0][q0];
            #pragma unroll
            for (int r = 0; r < PROWS; ++r) {               // static r -> no scratch
                float s = w0 * pr[r * PRP + 0] + w1 * pr[r * PRP + 1]
                        + w2 * pr[r * PRP + 2] + w3 * pr[r * PRP + 3];
                t_s[r][tid] = s;                            // lane-column: conflict-free
            }
            #pragma unroll
            for (int yi = 0; yi < TILE_H; ++yi) {
                int yl = ty0 + yi - iy0;                    // block-uniform
                if ((unsigned)yl < (unsigned)WIN) {
                    float4 w = fyw_s[yi];                   // broadcast
                    int rel = fyp_s[yi] - pbase;            // 0..8 (runtime -> LDS idx)
                    acc[yi] += w.x * t_s[rel + 0][tid] + w.y * t_s[rel + 1][tid]
                             + w.z * t_s[rel + 2][tid] + w.w * t_s[rel + 3][tid];
                }
            }
        }
        __syncthreads();   // protect patch_s/den_x/fyw before next stroke
    }

    // coalesced store; tiles partition the image -> every pixel written once
    float* o = out + (((size_t)b * NC + cc) * IMG_H + ty0) * IMG_W + xg;
    #pragma unroll
    for (int yi = 0; yi < TILE_H; ++yi)
        o[(size_t)yi * IMG_W] = acc[yi];
}

extern "C" void kernel_launch(void* const* d_in, const int* in_sizes, int n_in,
                              void* d_out, int out_size, void* d_ws, size_t ws_size,
                              hipStream_t stream) {
    const float* brushes = (const float*)d_in[0];   // (16, 64, 2) f32
    const float* patches = (const float*)d_in[1];   // (16, 64, 3, 32, 32) f32
    float* out = (float*)d_out;                     // (16, 3, 256, 256) f32

    fused_kernel<<<NWG, 192, 0, stream>>>(brushes, patches, out);
}

// Round 8
// 28.556 us; speedup vs baseline: 1.4777x; 1.1230x over previous
//
#include <hip/hip_runtime.h>

#define IMG_W 256
#define IMG_H 256
#define EPSN 1e-7f
#define NS 50.0f            // 1/(2*0.1^2)
#define NB 16
#define NN 64
#define NC 3
#define PH 32
#define PW 32
#define WIN 36              // stroke footprint window
#define PR 12               // staged patch rows per stroke
#define RST 56              // LDS row stride in floats (224B)

#define TILE_W 64
#define TILE_H 8
#define TPI 128             // tiles per image
#define NWG (NB * TPI)      // 2048 blocks

// One block per 64x8 tile, fully fused, vectorized inner loops.
// Thread = (c, ysub, xgrp): owns 4 consecutive x outputs x 2 y rows.
__global__ __launch_bounds__(192)
void fused_kernel(const float* __restrict__ brushes,
                  const float* __restrict__ patches,
                  float* __restrict__ out) {
    __shared__ float2 gxy_s[NN];
    __shared__ int    sPack[NN];
    __shared__ int    sCnt;
    __shared__ float  patch_s[NC * PR * RST];   // ~7.9 KB

    // XCD-contiguous swizzle: each XCD owns 256 consecutive tiles = 2 images
    int blk = blockIdx.x;
    blk = (blk & 7) * (NWG >> 3) + (blk >> 3);

    const int b    = blk >> 7;
    const int t7   = blk & 127;
    const int ty0  = (t7 >> 2) * TILE_H;
    const int tx0  = (t7 & 3) * TILE_W;
    const int tid  = threadIdx.x;
    const int cc   = tid >> 6;                  // channel
    const int lane = tid & 63;
    const int ysub = lane >> 4;                 // 0..3 -> y rows 2*ysub, 2*ysub+1
    const int xgrp = lane & 15;                 // 0..15 -> x group of 4
    const int ax0  = tx0 + xgrp * 4;
    const int ay0  = ty0 + ysub * 2;

    // --- wave 0: fused per-image min/max norm + ballot overlap list ---
    if (tid < 64) {
        float2 v = ((const float2*)brushes)[b * NN + tid];
        float mnx = v.x, mxx = v.x, mny = v.y, mxy = v.y;
        #pragma unroll
        for (int off = 32; off > 0; off >>= 1) {
            mnx = fminf(mnx, __shfl_xor(mnx, off));
            mxx = fmaxf(mxx, __shfl_xor(mxx, off));
            mny = fminf(mny, __shfl_xor(mny, off));
            mxy = fmaxf(mxy, __shfl_xor(mxy, off));
        }
        float gx = (v.x - mnx) / (mxx - mnx + EPSN) * (float)IMG_W;
        float gy = (v.y - mny) / (mxy - mny + EPSN) * (float)IMG_H;
        gxy_s[tid] = make_float2(gx, gy);

        int ix0 = (int)floorf(gx) - 17;
        int iy0 = (int)floorf(gy) - 17;
        bool ov = (ix0 <= tx0 + TILE_W - 1) && (ix0 + WIN - 1 >= tx0) &&
                  (iy0 <= ty0 + TILE_H - 1) && (iy0 + WIN - 1 >= ty0);
        unsigned long long mask = __ballot(ov);
        if (ov) {
            int pos = __popcll(mask & ((1ull << tid) - 1));
            sPack[pos] = tid;
        }
        if (tid == 0) sCnt = (int)__popcll(mask);
    }
    // zero LDS pads once: j in [0,8) U [40,56) per (c,row); staging never
    // overwrites them, so out-of-range taps always read exact 0.
    for (int u = tid; u < NC * PR * 24; u += 192) {
        int row = u / 24, rem = u - row * 24;
        int j = (rem < 8) ? rem : rem + 32;
        patch_s[row * RST + j] = 0.f;
    }
    __syncthreads();
    const int cnt = sCnt;

    float acc[2][4];
    #pragma unroll
    for (int j = 0; j < 2; ++j)
        #pragma unroll
        for (int o = 0; o < 4; ++o) acc[j][o] = 0.f;

    for (int i = 0; i < cnt; ++i) {
        const int n = sPack[i];
        const float2 g = gxy_s[n];

        // block-uniform staged row base (unclamped; p0(yi) = pbase + yi exactly)
        const float zy0 = (float)ty0 - g.y + 15.4f;
        const int pbase = (int)floorf(zy0) - 1;

        // ---- stage 12 rows (zero rows outside [0,31]) ----
        for (int u = tid; u < NC * PR * 8; u += 192) {
            int c  = u / (PR * 8);
            int rm = u - c * (PR * 8);
            int r  = rm >> 3, q4 = (rm & 7) << 2;
            int src = pbase + r;
            float4 v = make_float4(0.f, 0.f, 0.f, 0.f);
            if (src >= 0 && src <= 31)
                v = *(const float4*)(patches +
                      ((size_t)(b * NN + n) * NC + c) * (PH * PW) + src * PW + q4);
            *(float4*)&patch_s[(c * PR + r) * RST + 8 + q4] = v;
        }
        __syncthreads();

        const float zx0 = (float)ax0 - g.x + 15.5f;
        const int   q00 = (int)floorf(zx0) - 1;

        if (q00 >= -6 && q00 <= 31) {           // group has taps in [0,31]
            // --- 4 x-Gaussians; their sum IS the (interior) denominator ---
            const float phx = zx0 - floorf(zx0);
            float Ex[4], W[4];
            #pragma unroll
            for (int k = 0; k < 4; ++k) {
                float d = phx + (float)(1 - k);
                Ex[k] = __expf(-NS * d * d);
            }
            float Sx  = ((Ex[0] + Ex[1]) + (Ex[2] + Ex[3]));
            float Dxc = 1.f / (Sx + EPSN);
            #pragma unroll
            for (int k = 0; k < 4; ++k) W[k] = Ex[k] * Dxc;

            const int qbj = (q00 + 8) & ~3;     // aligned LDS j base (0..36)
            const int m   = (q00 + 8) & 3;      // stroke-uniform

            float t[5][4];
            auto rows = [&](auto Mc) {
                constexpr int M = Mc.value;
                #pragma unroll
                for (int rr = 0; rr < 5; ++rr) {
                    const float* rp = &patch_s[(cc * PR + 2 * ysub + rr) * RST + qbj];
                    float4 A  = *(const float4*)(rp);
                    float4 Bv = *(const float4*)(rp + 4);
                    float4 Cv = *(const float4*)(rp + 8);
                    float pv[12] = {A.x, A.y, A.z, A.w, Bv.x, Bv.y, Bv.z, Bv.w,
                                    Cv.x, Cv.y, Cv.z, Cv.w};
                    #pragma unroll
                    for (int o = 0; o < 4; ++o)
                        t[rr][o] = W[0] * pv[M + o]     + W[1] * pv[M + o + 1]
                                 + W[2] * pv[M + o + 2] + W[3] * pv[M + o + 3];
                }
            };
            switch (m) {
                case 0: rows(std::integral_constant<int, 0>{}); break;
                case 1: rows(std::integral_constant<int, 1>{}); break;
                case 2: rows(std::integral_constant<int, 2>{}); break;
                default: rows(std::integral_constant<int, 3>{}); break;
            }

            // --- x boundary-denominator correction (tap q=31 clipped at a=272) ---
            if (g.x > 255.0f) {
                float cx31 = g.x + 15.5f;
                float dc   = 272.f - cx31;
                float c272 = __expf(-NS * dc * dc);
                float dD   = 1.f / (Sx - c272 + EPSN) - Dxc;
                float e31[4];
                #pragma unroll
                for (int o = 0; o < 4; ++o) {
                    float d = zx0 + (float)o - 31.f;
                    e31[o] = __expf(-NS * d * d) * dD;   // 0 unless tap31 in window
                }
                #pragma unroll
                for (int rr = 0; rr < 5; ++rr) {
                    float p31 = patch_s[(cc * PR + 2 * ysub + rr) * RST + 8 + 31];
                    #pragma unroll
                    for (int o = 0; o < 4; ++o) t[rr][o] += e31[o] * p31;
                }
            }

            // --- y weights (shared by both owned rows; exact lattice shift) ---
            const float psy = zy0 - floorf(zy0);
            float Ey[4];
            #pragma unroll
            for (int k = 0; k < 4; ++k) {
                float d = psy + (float)(1 - k);
                Ey[k] = __expf(-NS * d * d);
            }
            float Sy  = ((Ey[0] + Ey[1]) + (Ey[2] + Ey[3]));
            float Dyc = (1.f / (Sy + EPSN)) * (1.f / (float)NN);
            float wyA[4], wyB[4];
            #pragma unroll
            for (int k = 0; k < 4; ++k) { wyA[k] = Ey[k] * Dyc; wyB[k] = wyA[k]; }
            if (g.y > 254.9f) {                 // tap p=31 clipped at b=272
                float cy31 = g.y + 15.6f;
                float dc   = 272.f - cy31;
                float c272 = __expf(-NS * dc * dc);
                float Dy31 = (1.f / (Sy - c272 + EPSN)) * (1.f / (float)NN);
                #pragma unroll
                for (int k = 0; k < 4; ++k) {
                    if (pbase + 2 * ysub + 0 + k == 31) wyA[k] = Ey[k] * Dy31;
                    if (pbase + 2 * ysub + 1 + k == 31) wyB[k] = Ey[k] * Dy31;
                }
            }

            // --- y-combine: static indices, taps row r = yi + k ---
            #pragma unroll
            for (int o = 0; o < 4; ++o) {
                acc[0][o] += wyA[0] * t[0][o] + wyA[1] * t[1][o]
                           + wyA[2] * t[2][o] + wyA[3] * t[3][o];
                acc[1][o] += wyB[0] * t[1][o] + wyB[1] * t[2][o]
                           + wyB[2] * t[3][o] + wyB[3] * t[4][o];
            }
        }
        __syncthreads();   // protect patch_s before next stroke's staging
    }

    // coalesced float4 stores; tiles partition the image
    #pragma unroll
    for (int j = 0; j < 2; ++j) {
        float* o = out + (((size_t)b * NC + cc) * IMG_H + ay0 + j) * IMG_W + ax0;
        *(float4*)o = make_float4(acc[j][0], acc[j][1], acc[j][2], acc[j][3]);
    }
}

extern "C" void kernel_launch(void* const* d_in, const int* in_sizes, int n_in,
                              void* d_out, int out_size, void* d_ws, size_t ws_size,
                              hipStream_t stream) {
    const float* brushes = (const float*)d_in[0];   // (16, 64, 2) f32
    const float* patches = (const float*)d_in[1];   // (16, 64, 3, 32, 32) f32
    float* out = (float*)d_out;                     // (16, 3, 256, 256) f32

    fused_kernel<<<NWG, 192, 0, stream>>>(brushes, patches, out);
}

// Round 10
// 27.911 us; speedup vs baseline: 1.5119x; 1.0231x over previous
//
#include <hip/hip_runtime.h>
#include <type_traits>

#define IMG_W 256
#define IMG_H 256
#define EPSN 1e-7f
#define NS 50.0f            // 1/(2*0.1^2)
#define NB 16
#define NN 64
#define NC 3
#define PH 32
#define PW 32
#define WIN 36              // stroke footprint window
#define TILE_W 64
#define TILE_H 8
#define TPI 128             // tiles per image
#define NWG (NB * TPI)      // 2048 blocks

// One block per 64x8 tile. Stroke loop is barrier-free and LDS-free:
// per-thread clamped global loads (L1/L2-hot). Edge exactness:
//   - chunks are 4-aligned and patch bounds (0,32) are 4-aligned rel. to qg,
//     so each 4-col chunk is entirely real or entirely phantom -> one
//     validity mask per chunk (phantom taps contribute exact 0).
//   - row (y) validity folded into y-weights.
//   - clipped-normalizer corrections only where the clipped term is
//     non-negligible (gx>255 / gy>254.9), per-tap-31.
__global__ __launch_bounds__(192)
void fused_kernel(const float* __restrict__ brushes,
                  const float* __restrict__ patches,
                  float* __restrict__ out) {
    __shared__ float2 sG[NN];
    __shared__ int    sN[NN];
    __shared__ int    sCnt;

    // XCD-contiguous swizzle: each XCD owns 256 consecutive tiles = 2 images
    int blk = blockIdx.x;
    blk = (blk & 7) * (NWG >> 3) + (blk >> 3);

    const int b    = blk >> 7;
    const int t7   = blk & 127;
    const int ty0  = (t7 >> 2) * TILE_H;
    const int tx0  = (t7 & 3) * TILE_W;
    const int tid  = threadIdx.x;
    const int cc   = tid >> 6;                  // channel
    const int lane = tid & 63;
    const int ysub = lane >> 4;                 // owns y rows 2*ysub, 2*ysub+1
    const int xgrp = lane & 15;                 // owns x group of 4
    const int ax0  = tx0 + xgrp * 4;
    const int ay0  = ty0 + ysub * 2;

    // --- wave 0: fused per-image min/max norm + ballot overlap list ---
    if (tid < 64) {
        float2 v = ((const float2*)brushes)[b * NN + tid];
        float mnx = v.x, mxx = v.x, mny = v.y, mxy = v.y;
        #pragma unroll
        for (int off = 32; off > 0; off >>= 1) {
            mnx = fminf(mnx, __shfl_xor(mnx, off));
            mxx = fmaxf(mxx, __shfl_xor(mxx, off));
            mny = fminf(mny, __shfl_xor(mny, off));
            mxy = fmaxf(mxy, __shfl_xor(mxy, off));
        }
        float gx = (v.x - mnx) / (mxx - mnx + EPSN) * (float)IMG_W;
        float gy = (v.y - mny) / (mxy - mny + EPSN) * (float)IMG_H;

        int ix0 = (int)floorf(gx) - 17;
        int iy0 = (int)floorf(gy) - 17;
        bool ov = (ix0 <= tx0 + TILE_W - 1) && (ix0 + WIN - 1 >= tx0) &&
                  (iy0 <= ty0 + TILE_H - 1) && (iy0 + WIN - 1 >= ty0);
        unsigned long long mask = __ballot(ov);
        if (ov) {
            int pos = __popcll(mask & ((1ull << tid) - 1));
            sN[pos] = tid;
            sG[pos] = make_float2(gx, gy);
        }
        if (tid == 0) sCnt = (int)__popcll(mask);
    }
    __syncthreads();                            // only barrier in the kernel
    const int cnt = sCnt;

    float acc[2][4];
    #pragma unroll
    for (int j = 0; j < 2; ++j)
        #pragma unroll
        for (int o = 0; o < 4; ++o) acc[j][o] = 0.f;

    const float* Pcb = patches + (size_t)b * NN * (NC * PH * PW) + cc * (PH * PW);

    for (int i = 0; i < cnt; ++i) {
        const float2 g = sG[i];                 // LDS broadcast
        const int    n = sN[i];
        const float* Pc = Pcb + (size_t)n * (NC * PH * PW);

        const float zy0 = (float)ty0 - g.y + 15.4f;
        const int pbase = (int)floorf(zy0) - 1; // p0(yi) = pbase + yi exactly
        const float zx0 = (float)ax0 - g.x + 15.5f;
        const int   q00 = (int)floorf(zx0) - 1;

        if (q00 >= -6 && q00 <= 31) {           // R7-proven active window
            // --- 4 x-Gaussians; their lattice sum IS the (interior) denom ---
            const float phx = zx0 - floorf(zx0);
            float Ex[4], W[4];
            #pragma unroll
            for (int k = 0; k < 4; ++k) {
                float d = phx + (float)(1 - k);
                Ex[k] = __expf(-NS * d * d);
            }
            float Sx  = ((Ex[0] + Ex[1]) + (Ex[2] + Ex[3]));
            float Dxc = 1.f / (Sx + EPSN);
            #pragma unroll
            for (int k = 0; k < 4; ++k) W[k] = Ex[k] * Dxc;

            const int qg = ((q00 + 8) & ~3) - 8;    // [-8,28], multiple of 4
            const int M  = (q00 + 8) & 3;           // stroke-uniform
            // per-chunk validity: chunk [s, s+3] real iff 0 <= s <= 28
            const int s1 = qg + 4, s2 = qg + 8;
            const float m0 = (qg >= 0 && qg <= 28) ? 1.f : 0.f;
            const float m1 = (s1 >= 0 && s1 <= 28) ? 1.f : 0.f;
            const float m2 = (s2 >= 0 && s2 <= 28) ? 1.f : 0.f;
            const int c0 = min(max(qg, 0), 28);     // clamped addresses
            const int c1 = min(max(s1, 0), 28);
            const int c2 = min(max(s2, 0), 28);

            float t[5][4];
            auto rows = [&](auto Mc) {
                constexpr int Mv = Mc.value;
                #pragma unroll
                for (int rr = 0; rr < 5; ++rr) {
                    int src = min(max(pbase + 2 * ysub + rr, 0), 31);
                    const float* rp = Pc + (src << 5);
                    float4 A  = *(const float4*)(rp + c0);
                    float4 Bv = *(const float4*)(rp + c1);
                    float4 Cv = *(const float4*)(rp + c2);
                    float pv[12] = {A.x * m0, A.y * m0, A.z * m0, A.w * m0,
                                    Bv.x * m1, Bv.y * m1, Bv.z * m1, Bv.w * m1,
                                    Cv.x * m2, Cv.y * m2, Cv.z * m2, Cv.w * m2};
                    #pragma unroll
                    for (int o = 0; o < 4; ++o)
                        t[rr][o] = W[0] * pv[Mv + o]     + W[1] * pv[Mv + o + 1]
                                 + W[2] * pv[Mv + o + 2] + W[3] * pv[Mv + o + 3];
                }
            };
            switch (M) {
                case 0: rows(std::integral_constant<int, 0>{}); break;
                case 1: rows(std::integral_constant<int, 1>{}); break;
                case 2: rows(std::integral_constant<int, 2>{}); break;
                default: rows(std::integral_constant<int, 3>{}); break;
            }

            // --- x boundary-denominator correction (a=272 clipped, tap 31) ---
            if (g.x > 255.0f) {
                float cx31 = g.x + 15.5f;
                float dc   = 272.f - cx31;
                float c272 = __expf(-NS * dc * dc);
                float dD   = 1.f / (Sx - c272 + EPSN) - Dxc;
                float e31[4];
                #pragma unroll
                for (int o = 0; o < 4; ++o) {
                    float d = zx0 + (float)o - 31.f;
                    e31[o] = __expf(-NS * d * d) * dD;  // self-gating (0 if far)
                }
                #pragma unroll
                for (int rr = 0; rr < 5; ++rr) {
                    int src = min(max(pbase + 2 * ysub + rr, 0), 31);
                    float p31 = Pc[(src << 5) + 31];
                    #pragma unroll
                    for (int o = 0; o < 4; ++o) t[rr][o] += e31[o] * p31;
                }
            }

            // --- y weights: validity + boundary correction folded in ---
            const float psy = zy0 - floorf(zy0);
            float Ey[4];
            #pragma unroll
            for (int k = 0; k < 4; ++k) {
                float d = psy + (float)(1 - k);
                Ey[k] = __expf(-NS * d * d);
            }
            float Sy   = ((Ey[0] + Ey[1]) + (Ey[2] + Ey[3]));
            float DyC  = (1.f / (Sy + EPSN)) * (1.0f / (float)NN);
            float Dy31 = DyC;
            if (g.y > 254.9f) {                 // b=272 clipped for tap row 31
                float cy31 = g.y + 15.6f;
                float dc   = 272.f - cy31;
                float c272 = __expf(-NS * dc * dc);
                Dy31 = (1.f / (Sy - c272 + EPSN)) * (1.0f / (float)NN);
            }
            float wyA[4], wyB[4];
            #pragma unroll
            for (int k = 0; k < 4; ++k) {
                int rA = pbase + 2 * ysub + k;
                int rB = rA + 1;
                wyA[k] = ((unsigned)rA < 32u) ? Ey[k] * ((rA == 31) ? Dy31 : DyC) : 0.f;
                wyB[k] = ((unsigned)rB < 32u) ? Ey[k] * ((rB == 31) ? Dy31 : DyC) : 0.f;
            }

            // --- y-combine (all indices static) ---
            #pragma unroll
            for (int o = 0; o < 4; ++o) {
                acc[0][o] += wyA[0] * t[0][o] + wyA[1] * t[1][o]
                           + wyA[2] * t[2][o] + wyA[3] * t[3][o];
                acc[1][o] += wyB[0] * t[1][o] + wyB[1] * t[2][o]
                           + wyB[2] * t[3][o] + wyB[3] * t[4][o];
            }
        }
    }

    // coalesced float4 stores; tiles partition the image
    #pragma unroll
    for (int j = 0; j < 2; ++j) {
        float* o = out + (((size_t)b * NC + cc) * IMG_H + ay0 + j) * IMG_W + ax0;
        *(float4*)o = make_float4(acc[j][0], acc[j][1], acc[j][2], acc[j][3]);
    }
}

extern "C" void kernel_launch(void* const* d_in, const int* in_sizes, int n_in,
                              void* d_out, int out_size, void* d_ws, size_t ws_size,
                              hipStream_t stream) {
    const float* brushes = (const float*)d_in[0];   // (16, 64, 2) f32
    const float* patches = (const float*)d_in[1];   // (16, 64, 3, 32, 32) f32
    float* out = (float*)d_out;                     // (16, 3, 256, 256) f32

    fused_kernel<<<NWG, 192, 0, stream>>>(brushes, patches, out);
}